// Round 19
// baseline (237.875 us; speedup 1.0000x reference)
//
#include <hip/hip_runtime.h>

#define BB 16
#define TT 12
#define NN 1024
#define DD 64
#define EE 32
#define MM (TT*NN)          // 12288 rows per batch
#define ROWS (BB*MM)        // 196608 total rows
#define CPB2N 96            // k2 blocks per batch -> grid 1536; 1 chunk/wave
#define S_ITER (384/(CPB2N*4))   // chunks per wave
#define CPB4 64             // k14 blocks per batch -> grid 1024 = exactly 4 blocks/CU, 3 tiles/wave
#define LN_EPS 1e-5f
#define WSTRIDE 72          // padded bf16 row stride for W in LDS (144 B: 16B-aligned, 2-way bank)

typedef __attribute__((ext_vector_type(8))) short short8;
typedef __attribute__((ext_vector_type(4))) float f32x4;
typedef __attribute__((ext_vector_type(4))) int   int4v;

// pack two f32 -> one dword of 2 bf16 (RNE), low = a, high = b
__device__ __forceinline__ int cvt2(float a, float b){
  int r;
  asm("v_cvt_pk_bf16_f32 %0, %1, %2" : "=v"(r) : "v"(a), "v"(b));
  return r;
}
__device__ __forceinline__ unsigned short bf16of(float a){
  return (unsigned short)(cvt2(a, a) & 0xffff);
}
__device__ __forceinline__ float f32of(unsigned short h){
  return __builtin_bit_cast(float, (unsigned int)h << 16);
}
__device__ __forceinline__ float lo16f(int w){ return __builtin_bit_cast(float, (unsigned int)w << 16); }
__device__ __forceinline__ float hi16f(int w){ return __builtin_bit_cast(float, (unsigned int)w & 0xffff0000u); }

__device__ __forceinline__ short8 pack_hi8(const float* v){
  int4v w;
  w.x = cvt2(v[0], v[1]); w.y = cvt2(v[2], v[3]);
  w.z = cvt2(v[4], v[5]); w.w = cvt2(v[6], v[7]);
  return __builtin_bit_cast(short8, w);
}
__device__ __forceinline__ short8 pack_lo8(const float* v, short8 hi){
  const int4v wh = __builtin_bit_cast(int4v, hi);
  float r[8];
  r[0] = v[0] - lo16f(wh.x); r[1] = v[1] - hi16f(wh.x);
  r[2] = v[2] - lo16f(wh.y); r[3] = v[3] - hi16f(wh.y);
  r[4] = v[4] - lo16f(wh.z); r[5] = v[5] - hi16f(wh.z);
  r[6] = v[6] - lo16f(wh.w); r[7] = v[7] - hi16f(wh.w);
  return pack_hi8(r);
}

// ---------------- K2: full-MFMA hyper stage 1; finishes with atomicAdd into hf ----------------
__global__ __launch_bounds__(256, 3)
void k2_hyper1(const float* __restrict__ x, const float* __restrict__ clf,
               unsigned short* __restrict__ assign_hi, unsigned short* __restrict__ assign_lo,
               float* __restrict__ hf)
{
  __shared__ __align__(16) float lbuf[4224];   // union: amat 4x[32][33] | red 2x[32][65]
  const int lane = threadIdx.x & 63;
  const int wid  = threadIdx.x >> 6;
  const int l15  = lane & 15;
  const int lg   = lane >> 4;
  const int b    = blockIdx.x / CPB2N;
  const int blk  = blockIdx.x % CPB2N;
  float* amat = lbuf + wid*1056;               // [32][33] f32 per wave

  short8 bch[2][2], bcl[2][2];
  #pragma unroll
  for (int kc = 0; kc < 2; ++kc)
    #pragma unroll
    for (int nt = 0; nt < 2; ++nt){
      float v[8];
      #pragma unroll
      for (int j = 0; j < 8; ++j)
        v[j] = clf[(size_t)(32*kc + 8*lg + j)*EE + 16*nt + l15];
      bch[kc][nt] = pack_hi8(v);
      bcl[kc][nt] = pack_lo8(v, bch[kc][nt]);
    }

  f32x4 acc2[2][4];
  #pragma unroll
  for (int et = 0; et < 2; ++et)
    #pragma unroll
    for (int dt = 0; dt < 4; ++dt) acc2[et][dt] = (f32x4){0.f,0.f,0.f,0.f};

  const int wslot = blk*4 + wid;               // 0..CPB2N*4-1
  #pragma unroll 1
  for (int s = 0; s < S_ITER; ++s){
    const int c = wslot + s*(CPB2N*4);         // chunk id, covers 0..383 exactly once
    const size_t grb = (size_t)b*MM + (size_t)c*32;

    #pragma unroll 1
    for (int h = 0; h < 2; ++h){
      short8 axh[2], axl[2];
      #pragma unroll
      for (int kc = 0; kc < 2; ++kc){
        const float* p = x + (grb + 16*h + l15)*DD + 32*kc + 8*lg;
        float v[8];
        const float4 p0 = *reinterpret_cast<const float4*>(p);
        const float4 p1 = *reinterpret_cast<const float4*>(p + 4);
        v[0]=p0.x; v[1]=p0.y; v[2]=p0.z; v[3]=p0.w;
        v[4]=p1.x; v[5]=p1.y; v[6]=p1.z; v[7]=p1.w;
        axh[kc] = pack_hi8(v); axl[kc] = pack_lo8(v, axh[kc]);
      }
      f32x4 accL[2] = {(f32x4){0.f,0.f,0.f,0.f},(f32x4){0.f,0.f,0.f,0.f}};
      #pragma unroll
      for (int kc = 0; kc < 2; ++kc)
        #pragma unroll
        for (int nt = 0; nt < 2; ++nt){
          accL[nt] = __builtin_amdgcn_mfma_f32_16x16x32_bf16(axh[kc], bch[kc][nt], accL[nt], 0, 0, 0);
          accL[nt] = __builtin_amdgcn_mfma_f32_16x16x32_bf16(axh[kc], bcl[kc][nt], accL[nt], 0, 0, 0);
          accL[nt] = __builtin_amdgcn_mfma_f32_16x16x32_bf16(axl[kc], bch[kc][nt], accL[nt], 0, 0, 0);
        }
      #pragma unroll
      for (int q = 0; q < 4; ++q){
        const float l0 = accL[0][q], l1 = accL[1][q];
        float mx = fmaxf(l0, l1);
        #pragma unroll
        for (int off = 8; off; off >>= 1) mx = fmaxf(mx, __shfl_xor(mx, off));
        const float e0 = expf(l0 - mx), e1 = expf(l1 - mx);
        float sm = e0 + e1;
        #pragma unroll
        for (int off = 8; off; off >>= 1) sm += __shfl_xor(sm, off);
        const float inv = 1.f / sm;
        const float a0 = e0*inv, a1 = e1*inv;
        const int rloc = 16*h + 4*lg + q;
        const size_t row = grb + rloc;
        const unsigned short h0 = bf16of(a0);
        const unsigned short h1 = bf16of(a1);
        assign_hi[row*EE + l15]      = h0;
        assign_hi[row*EE + 16 + l15] = h1;
        assign_lo[row*EE + l15]      = bf16of(a0 - f32of(h0));
        assign_lo[row*EE + 16 + l15] = bf16of(a1 - f32of(h1));
        amat[rloc*33 + l15]      = a0;
        amat[rloc*33 + 16 + l15] = a1;
      }
    }
    __builtin_amdgcn_wave_barrier();
    short8 a2h[2], a2l[2];
    #pragma unroll
    for (int et = 0; et < 2; ++et){
      float v[8];
      #pragma unroll
      for (int j = 0; j < 8; ++j)
        v[j] = amat[(8*lg + j)*33 + 16*et + l15];
      a2h[et] = pack_hi8(v); a2l[et] = pack_lo8(v, a2h[et]);
    }
    #pragma unroll
    for (int dt = 0; dt < 4; ++dt){
      float v[8];
      #pragma unroll
      for (int j = 0; j < 8; ++j)
        v[j] = x[(grb + 8*lg + j)*DD + 16*dt + l15];
      const short8 b2 = pack_hi8(v);
      #pragma unroll
      for (int et = 0; et < 2; ++et){
        acc2[et][dt] = __builtin_amdgcn_mfma_f32_16x16x32_bf16(a2h[et], b2, acc2[et][dt], 0, 0, 0);
        acc2[et][dt] = __builtin_amdgcn_mfma_f32_16x16x32_bf16(a2l[et], b2, acc2[et][dt], 0, 0, 0);
      }
    }
    __builtin_amdgcn_wave_barrier();
  }

  __syncthreads();
  float* red = lbuf;
  if (wid < 2){
    #pragma unroll
    for (int et = 0; et < 2; ++et)
      #pragma unroll
      for (int dt = 0; dt < 4; ++dt)
        #pragma unroll
        for (int q = 0; q < 4; ++q)
          red[wid*2080 + (16*et + 4*lg + q)*65 + 16*dt + l15] = acc2[et][dt][q];
  }
  __syncthreads();
  if (wid >= 2){
    #pragma unroll
    for (int et = 0; et < 2; ++et)
      #pragma unroll
      for (int dt = 0; dt < 4; ++dt)
        #pragma unroll
        for (int q = 0; q < 4; ++q)
          red[(wid-2)*2080 + (16*et + 4*lg + q)*65 + 16*dt + l15] += acc2[et][dt][q];
  }
  __syncthreads();
  for (int i = threadIdx.x; i < EE*DD; i += 256){
    const int e = i >> 6, d = i & 63;
    atomicAdd(&hf[(size_t)b*EE*DD + i], red[e*65 + d] + red[2080 + e*65 + d]);
  }
}

// ---------------- K14: ho preamble (LDS) + fused STGCN + hyper-combine; W fragments from LDS ----------------
// REQUIRES xin != xout (launcher ping-pongs): reads x[t-1] rows cross-tile.
__global__ __launch_bounds__(256, 2)
void k14_fused(const float* __restrict__ x,
               const float* __restrict__ W1, const float* __restrict__ b1,
               const float* __restrict__ W2, const float* __restrict__ b2,
               const float* __restrict__ lng, const float* __restrict__ lnb,
               const unsigned short* __restrict__ assign_hi,
               const unsigned short* __restrict__ assign_lo,
               const float* __restrict__ hf, const float* __restrict__ em,
               const float* __restrict__ hg, const float* __restrict__ hb,
               float* __restrict__ xout)
{
  // union: phase A {ems 4KB | hfs 8KB | hos 8KB} -> phase B {wlds 18.4KB}
  __shared__ __align__(16) unsigned char smem[20480];
  float* ems = (float*)smem;                   // [EE*EE]
  float* hfs = ems + EE*EE;                    // [EE*DD]
  float* hos = hfs + EE*DD;                    // [EE*DD]
  unsigned short* wlds = (unsigned short*)smem; // [2][64][WSTRIDE] bf16 (aliases all of the above)

  const int lane = threadIdx.x & 63;
  const int wid  = threadIdx.x >> 6;
  const int b    = blockIdx.x / CPB4;
  const int blk  = blockIdx.x % CPB4;
  const int l15  = lane & 15;
  const int lg   = lane >> 4;
  const int k0   = lg * 8;

  // ---- phase A: ho preamble (bit-identical math to former k3_edge) ----
  for (int i = threadIdx.x; i < EE*EE; i += 256) ems[i] = em[i];
  for (int i = threadIdx.x; i < EE*DD; i += 256) hfs[i] = hf[(size_t)b*EE*DD + i];
  __syncthreads();
  for (int i = threadIdx.x; i < EE*DD; i += 256){
    const int e = i >> 6, d = i & 63;
    float acc = 0.f;
    #pragma unroll
    for (int f = 0; f < EE; ++f) acc = fmaf(ems[e*EE+f], hfs[f*DD+d], acc);
    hos[i] = fmaxf(acc, 0.f) + hfs[e*DD+d];
  }
  __syncthreads();

  // ho fragments built from LDS (must complete before wlds overwrites hos)
  short8 bwh[4], bwl[4];
  #pragma unroll
  for (int nt = 0; nt < 4; ++nt){
    float v[8];
    #pragma unroll
    for (int j = 0; j < 8; ++j)
      v[j] = hos[(8*lg + j)*DD + l15 + 16*nt];
    bwh[nt] = pack_hi8(v);
    bwl[nt] = pack_lo8(v, bwh[nt]);
  }
  __syncthreads();

  // ---- phase B: stage W1/W2 as bf16 into LDS (same RNE conversion as before) ----
  {
    const float* Wm[2] = {W1, W2};
    for (int i = threadIdx.x; i < 2*DD*DD; i += 256){
      const int m = i >> 12;          // /4096
      const int rc = i & 4095;
      const int r = rc >> 6, c = rc & 63;
      wlds[m*(DD*WSTRIDE) + r*WSTRIDE + c] = bf16of(Wm[m][r*DD + c]);
    }
  }
  __syncthreads();

  float b1c[4], b2c[4], g1c[4], B1c[4], g2c[4], B2c[4];
  #pragma unroll
  for (int nt = 0; nt < 4; ++nt){
    b1c[nt] = b1[l15 + 16*nt];
    b2c[nt] = b2[l15 + 16*nt];
    g1c[nt] = lng[l15 + 16*nt];
    B1c[nt] = lnb[l15 + 16*nt];
    g2c[nt] = hg[l15 + 16*nt];
    B2c[nt] = hb[l15 + 16*nt];
  }

  const int tpb = MM / 16;                      // 768 tiles per batch; 3 tiles/wave at CPB4=64
  for (int tl = blk*4 + wid; tl < tpb; tl += CPB4*4){
    const size_t r0 = (size_t)b*MM + (size_t)tl*16;  // global row base
    const int t = (tl*16) >> 10;                // local frame index 0..11

    // ---- k1-part A-fragments ----
    const float* pc = x + (r0 + l15)*DD + k0;
    float4 a00 = *reinterpret_cast<const float4*>(pc);
    float4 a01 = *reinterpret_cast<const float4*>(pc + 4);
    float4 a10 = *reinterpret_cast<const float4*>(pc + 32);
    float4 a11 = *reinterpret_cast<const float4*>(pc + 36);
    if (t > 0){
      const float* pp = pc - (size_t)NN*DD;
      const float4 q00 = *reinterpret_cast<const float4*>(pp);
      const float4 q01 = *reinterpret_cast<const float4*>(pp + 4);
      const float4 q10 = *reinterpret_cast<const float4*>(pp + 32);
      const float4 q11 = *reinterpret_cast<const float4*>(pp + 36);
      a00.x = 0.5f*(a00.x+q00.x); a00.y = 0.5f*(a00.y+q00.y);
      a00.z = 0.5f*(a00.z+q00.z); a00.w = 0.5f*(a00.w+q00.w);
      a01.x = 0.5f*(a01.x+q01.x); a01.y = 0.5f*(a01.y+q01.y);
      a01.z = 0.5f*(a01.z+q01.z); a01.w = 0.5f*(a01.w+q01.w);
      a10.x = 0.5f*(a10.x+q10.x); a10.y = 0.5f*(a10.y+q10.y);
      a10.z = 0.5f*(a10.z+q10.z); a10.w = 0.5f*(a10.w+q10.w);
      a11.x = 0.5f*(a11.x+q11.x); a11.y = 0.5f*(a11.y+q11.y);
      a11.z = 0.5f*(a11.z+q11.z); a11.w = 0.5f*(a11.w+q11.w);
    } else {
      a00.x*=0.5f;a00.y*=0.5f;a00.z*=0.5f;a00.w*=0.5f;
      a01.x*=0.5f;a01.y*=0.5f;a01.z*=0.5f;a01.w*=0.5f;
      a10.x*=0.5f;a10.y*=0.5f;a10.z*=0.5f;a10.w*=0.5f;
      a11.x*=0.5f;a11.y*=0.5f;a11.z*=0.5f;a11.w*=0.5f;
    }
    // shared epilogue x loads (C-layout rows)
    float epi[4][4];
    #pragma unroll
    for (int q = 0; q < 4; ++q){
      const float* pr = x + (r0 + 4*lg + q)*DD + l15;
      #pragma unroll
      for (int nt = 0; nt < 4; ++nt) epi[q][nt] = pr[16*nt];
    }
    // k4-part A-fragments
    const short8 afh = *reinterpret_cast<const short8*>(assign_hi + (r0 + l15)*EE + 8*lg);
    const short8 afl = *reinterpret_cast<const short8*>(assign_lo + (r0 + l15)*EE + 8*lg);

    short8 af[2];
    {
      int4v w;
      w.x = cvt2(a00.x, a00.y); w.y = cvt2(a00.z, a00.w);
      w.z = cvt2(a01.x, a01.y); w.w = cvt2(a01.z, a01.w);
      af[0] = __builtin_bit_cast(short8, w);
      w.x = cvt2(a10.x, a10.y); w.y = cvt2(a10.z, a10.w);
      w.z = cvt2(a11.x, a11.y); w.w = cvt2(a11.z, a11.w);
      af[1] = __builtin_bit_cast(short8, w);
    }

    f32x4 acc1[2][4], acc4[4];
    #pragma unroll
    for (int m = 0; m < 2; ++m)
      #pragma unroll
      for (int nt = 0; nt < 4; ++nt) acc1[m][nt] = (f32x4){0.f,0.f,0.f,0.f};
    #pragma unroll
    for (int nt = 0; nt < 4; ++nt) acc4[nt] = (f32x4){0.f,0.f,0.f,0.f};

    // k1-part MFMAs with W fragments streamed from LDS
    #pragma unroll
    for (int kc = 0; kc < 2; ++kc){
      #pragma unroll
      for (int nt = 0; nt < 4; ++nt){
        const int off = (16*nt + l15)*WSTRIDE + 32*kc + 8*lg;
        const short8 w0 = *reinterpret_cast<const short8*>(wlds + off);
        const short8 w1 = *reinterpret_cast<const short8*>(wlds + DD*WSTRIDE + off);
        acc1[0][nt] = __builtin_amdgcn_mfma_f32_16x16x32_bf16(af[kc], w0, acc1[0][nt], 0, 0, 0);
        acc1[1][nt] = __builtin_amdgcn_mfma_f32_16x16x32_bf16(af[kc], w1, acc1[1][nt], 0, 0, 0);
      }
    }
    #pragma unroll
    for (int nt = 0; nt < 4; ++nt){
      acc4[nt] = __builtin_amdgcn_mfma_f32_16x16x32_bf16(afh, bwh[nt], acc4[nt], 0, 0, 0);
      acc4[nt] = __builtin_amdgcn_mfma_f32_16x16x32_bf16(afh, bwl[nt], acc4[nt], 0, 0, 0);
      acc4[nt] = __builtin_amdgcn_mfma_f32_16x16x32_bf16(afl, bwh[nt], acc4[nt], 0, 0, 0);
    }

    // ---- dual epilogue: LN1 (stgcn) and LN2 (hyper), interleaved shfl chains ----
    #pragma unroll
    for (int q = 0; q < 4; ++q){
      const size_t row = r0 + 4*lg + q;
      float s1[4], s2[4];
      float rs1 = 0.f, rs2 = 0.f;
      #pragma unroll
      for (int nt = 0; nt < 4; ++nt){
        const float g1 = acc1[0][nt][q] + b1c[nt];
        const float g2 = acc1[1][nt][q] + b2c[nt];
        s1[nt] = fmaxf(g1*g2, 0.f) + g1 + epi[q][nt];
        rs1 += s1[nt];
        s2[nt] = fmaxf(acc4[nt][q], 0.f) + epi[q][nt];
        rs2 += s2[nt];
      }
      #pragma unroll
      for (int off = 8; off; off >>= 1){ rs1 += __shfl_xor(rs1, off); rs2 += __shfl_xor(rs2, off); }
      const float m1 = rs1 * (1.f/DD);
      const float m2 = rs2 * (1.f/DD);
      float d1[4], d2[4]; float v1 = 0.f, v2 = 0.f;
      #pragma unroll
      for (int nt = 0; nt < 4; ++nt){
        d1[nt] = s1[nt] - m1; v1 = fmaf(d1[nt], d1[nt], v1);
        d2[nt] = s2[nt] - m2; v2 = fmaf(d2[nt], d2[nt], v2);
      }
      #pragma unroll
      for (int off = 8; off; off >>= 1){ v1 += __shfl_xor(v1, off); v2 += __shfl_xor(v2, off); }
      const float i1 = rsqrtf(v1 * (1.f/DD) + LN_EPS);
      const float i2 = rsqrtf(v2 * (1.f/DD) + LN_EPS);
      #pragma unroll
      for (int nt = 0; nt < 4; ++nt){
        const float o1 = d1[nt]*i1*g1c[nt] + B1c[nt];
        const float o2 = d2[nt]*i2*g2c[nt] + B2c[nt];
        xout[row*DD + l15 + 16*nt] = 0.5f*(o1 + o2);
      }
    }
  }
}

extern "C" void kernel_launch(void* const* d_in, const int* in_sizes, int n_in,
                              void* d_out, int out_size, void* d_ws, size_t ws_size,
                              hipStream_t stream)
{
  (void)in_sizes; (void)n_in; (void)out_size; (void)ws_size;
  const float* x0  = (const float*)d_in[0];
  const float* W1  = (const float*)d_in[1];
  const float* b1  = (const float*)d_in[2];
  const float* W2  = (const float*)d_in[3];
  const float* b2  = (const float*)d_in[4];
  const float* lng = (const float*)d_in[5];
  const float* lnb = (const float*)d_in[6];
  const float* clf = (const float*)d_in[7];
  const float* em  = (const float*)d_in[8];
  const float* hg  = (const float*)d_in[9];
  const float* hb  = (const float*)d_in[10];
  float* out = (float*)d_out;

  // workspace: x ping f32 | hf3 f32 [3][BB][EE*DD] (384 KB, one upfront memset) | assign hi/lo bf16
  float* ws_x = (float*)d_ws;
  float* hf3  = ws_x + (size_t)ROWS*DD;
  unsigned short* assign_hi = (unsigned short*)(hf3 + (size_t)3*BB*EE*DD);
  unsigned short* assign_lo = assign_hi + (size_t)ROWS*EE;

  // ping-pong so xin != xout at EVERY depth (k14 reads t-1 rows cross-tile):
  // depth 0: x0 -> d_out ; depth 1: d_out -> ws_x ; depth 2: ws_x -> d_out (final)
  const float* xin_seq[3]  = { x0, out, ws_x };
  float*       xout_seq[3] = { out, ws_x, out };

  hipMemsetAsync(hf3, 0, (size_t)3*BB*EE*DD*sizeof(float), stream);
  for (int i = 0; i < 3; ++i){
    const float* xin = xin_seq[i];
    float* xout = xout_seq[i];
    float* hf = hf3 + (size_t)i*BB*EE*DD;
    k2_hyper1<<<BB*CPB2N, 256, 0, stream>>>(xin, clf, assign_hi, assign_lo, hf);
    k14_fused<<<BB*CPB4, 256, 0, stream>>>(xin, W1 + i*DD*DD, b1 + i*DD,
                                           W2 + i*DD*DD, b2 + i*DD,
                                           lng + i*DD, lnb + i*DD,
                                           assign_hi, assign_lo, hf, em,
                                           hg, hb, xout);
  }
}

// Round 20
// 232.587 us; speedup vs baseline: 1.0227x; 1.0227x over previous
//
#include <hip/hip_runtime.h>

#define BB 16
#define TT 12
#define NN 1024
#define DD 64
#define EE 32
#define MM (TT*NN)          // 12288 rows per batch
#define ROWS (BB*MM)        // 196608 total rows
#define CPB2N 96            // k2 blocks per batch -> grid 1536; 1 chunk/wave
#define S_ITER (384/(CPB2N*4))   // chunks per wave
#define CPB4 96             // k14 blocks per batch -> grid 1536 = exactly 6 blocks/CU at VGPR=84, 2 tiles/wave
#define LN_EPS 1e-5f
#define WSTRIDE 72          // padded bf16 row stride for W in LDS

typedef __attribute__((ext_vector_type(8))) short short8;
typedef __attribute__((ext_vector_type(4))) float f32x4;
typedef __attribute__((ext_vector_type(4))) int   int4v;

// pack two f32 -> one dword of 2 bf16 (RNE), low = a, high = b
__device__ __forceinline__ int cvt2(float a, float b){
  int r;
  asm("v_cvt_pk_bf16_f32 %0, %1, %2" : "=v"(r) : "v"(a), "v"(b));
  return r;
}
__device__ __forceinline__ unsigned short bf16of(float a){
  return (unsigned short)(cvt2(a, a) & 0xffff);
}
__device__ __forceinline__ float f32of(unsigned short h){
  return __builtin_bit_cast(float, (unsigned int)h << 16);
}
__device__ __forceinline__ float lo16f(int w){ return __builtin_bit_cast(float, (unsigned int)w << 16); }
__device__ __forceinline__ float hi16f(int w){ return __builtin_bit_cast(float, (unsigned int)w & 0xffff0000u); }

__device__ __forceinline__ short8 pack_hi8(const float* v){
  int4v w;
  w.x = cvt2(v[0], v[1]); w.y = cvt2(v[2], v[3]);
  w.z = cvt2(v[4], v[5]); w.w = cvt2(v[6], v[7]);
  return __builtin_bit_cast(short8, w);
}
__device__ __forceinline__ short8 pack_lo8(const float* v, short8 hi){
  const int4v wh = __builtin_bit_cast(int4v, hi);
  float r[8];
  r[0] = v[0] - lo16f(wh.x); r[1] = v[1] - hi16f(wh.x);
  r[2] = v[2] - lo16f(wh.y); r[3] = v[3] - hi16f(wh.y);
  r[4] = v[4] - lo16f(wh.z); r[5] = v[5] - hi16f(wh.z);
  r[6] = v[6] - lo16f(wh.w); r[7] = v[7] - hi16f(wh.w);
  return pack_hi8(r);
}

// ---------------- K2: full-MFMA hyper stage 1; finishes with atomicAdd into hf ----------------
__global__ __launch_bounds__(256, 3)
void k2_hyper1(const float* __restrict__ x, const float* __restrict__ clf,
               unsigned short* __restrict__ assign_hi, unsigned short* __restrict__ assign_lo,
               float* __restrict__ hf)
{
  __shared__ __align__(16) float lbuf[4224];   // union: amat 4x[32][33] | red 2x[32][65]
  const int lane = threadIdx.x & 63;
  const int wid  = threadIdx.x >> 6;
  const int l15  = lane & 15;
  const int lg   = lane >> 4;
  const int b    = blockIdx.x / CPB2N;
  const int blk  = blockIdx.x % CPB2N;
  float* amat = lbuf + wid*1056;               // [32][33] f32 per wave

  short8 bch[2][2], bcl[2][2];
  #pragma unroll
  for (int kc = 0; kc < 2; ++kc)
    #pragma unroll
    for (int nt = 0; nt < 2; ++nt){
      float v[8];
      #pragma unroll
      for (int j = 0; j < 8; ++j)
        v[j] = clf[(size_t)(32*kc + 8*lg + j)*EE + 16*nt + l15];
      bch[kc][nt] = pack_hi8(v);
      bcl[kc][nt] = pack_lo8(v, bch[kc][nt]);
    }

  f32x4 acc2[2][4];
  #pragma unroll
  for (int et = 0; et < 2; ++et)
    #pragma unroll
    for (int dt = 0; dt < 4; ++dt) acc2[et][dt] = (f32x4){0.f,0.f,0.f,0.f};

  const int wslot = blk*4 + wid;               // 0..CPB2N*4-1
  #pragma unroll 1
  for (int s = 0; s < S_ITER; ++s){
    const int c = wslot + s*(CPB2N*4);         // chunk id, covers 0..383 exactly once
    const size_t grb = (size_t)b*MM + (size_t)c*32;

    #pragma unroll 1
    for (int h = 0; h < 2; ++h){
      short8 axh[2], axl[2];
      #pragma unroll
      for (int kc = 0; kc < 2; ++kc){
        const float* p = x + (grb + 16*h + l15)*DD + 32*kc + 8*lg;
        float v[8];
        const float4 p0 = *reinterpret_cast<const float4*>(p);
        const float4 p1 = *reinterpret_cast<const float4*>(p + 4);
        v[0]=p0.x; v[1]=p0.y; v[2]=p0.z; v[3]=p0.w;
        v[4]=p1.x; v[5]=p1.y; v[6]=p1.z; v[7]=p1.w;
        axh[kc] = pack_hi8(v); axl[kc] = pack_lo8(v, axh[kc]);
      }
      f32x4 accL[2] = {(f32x4){0.f,0.f,0.f,0.f},(f32x4){0.f,0.f,0.f,0.f}};
      #pragma unroll
      for (int kc = 0; kc < 2; ++kc)
        #pragma unroll
        for (int nt = 0; nt < 2; ++nt){
          accL[nt] = __builtin_amdgcn_mfma_f32_16x16x32_bf16(axh[kc], bch[kc][nt], accL[nt], 0, 0, 0);
          accL[nt] = __builtin_amdgcn_mfma_f32_16x16x32_bf16(axh[kc], bcl[kc][nt], accL[nt], 0, 0, 0);
          accL[nt] = __builtin_amdgcn_mfma_f32_16x16x32_bf16(axl[kc], bch[kc][nt], accL[nt], 0, 0, 0);
        }
      #pragma unroll
      for (int q = 0; q < 4; ++q){
        const float l0 = accL[0][q], l1 = accL[1][q];
        float mx = fmaxf(l0, l1);
        #pragma unroll
        for (int off = 8; off; off >>= 1) mx = fmaxf(mx, __shfl_xor(mx, off));
        const float e0 = expf(l0 - mx), e1 = expf(l1 - mx);
        float sm = e0 + e1;
        #pragma unroll
        for (int off = 8; off; off >>= 1) sm += __shfl_xor(sm, off);
        const float inv = 1.f / sm;
        const float a0 = e0*inv, a1 = e1*inv;
        const int rloc = 16*h + 4*lg + q;
        const size_t row = grb + rloc;
        const unsigned short h0 = bf16of(a0);
        const unsigned short h1 = bf16of(a1);
        assign_hi[row*EE + l15]      = h0;
        assign_hi[row*EE + 16 + l15] = h1;
        assign_lo[row*EE + l15]      = bf16of(a0 - f32of(h0));
        assign_lo[row*EE + 16 + l15] = bf16of(a1 - f32of(h1));
        amat[rloc*33 + l15]      = a0;
        amat[rloc*33 + 16 + l15] = a1;
      }
    }
    __builtin_amdgcn_wave_barrier();
    short8 a2h[2], a2l[2];
    #pragma unroll
    for (int et = 0; et < 2; ++et){
      float v[8];
      #pragma unroll
      for (int j = 0; j < 8; ++j)
        v[j] = amat[(8*lg + j)*33 + 16*et + l15];
      a2h[et] = pack_hi8(v); a2l[et] = pack_lo8(v, a2h[et]);
    }
    #pragma unroll
    for (int dt = 0; dt < 4; ++dt){
      float v[8];
      #pragma unroll
      for (int j = 0; j < 8; ++j)
        v[j] = x[(grb + 8*lg + j)*DD + 16*dt + l15];
      const short8 b2 = pack_hi8(v);
      #pragma unroll
      for (int et = 0; et < 2; ++et){
        acc2[et][dt] = __builtin_amdgcn_mfma_f32_16x16x32_bf16(a2h[et], b2, acc2[et][dt], 0, 0, 0);
        acc2[et][dt] = __builtin_amdgcn_mfma_f32_16x16x32_bf16(a2l[et], b2, acc2[et][dt], 0, 0, 0);
      }
    }
    __builtin_amdgcn_wave_barrier();
  }

  __syncthreads();
  float* red = lbuf;
  if (wid < 2){
    #pragma unroll
    for (int et = 0; et < 2; ++et)
      #pragma unroll
      for (int dt = 0; dt < 4; ++dt)
        #pragma unroll
        for (int q = 0; q < 4; ++q)
          red[wid*2080 + (16*et + 4*lg + q)*65 + 16*dt + l15] = acc2[et][dt][q];
  }
  __syncthreads();
  if (wid >= 2){
    #pragma unroll
    for (int et = 0; et < 2; ++et)
      #pragma unroll
      for (int dt = 0; dt < 4; ++dt)
        #pragma unroll
        for (int q = 0; q < 4; ++q)
          red[(wid-2)*2080 + (16*et + 4*lg + q)*65 + 16*dt + l15] += acc2[et][dt][q];
  }
  __syncthreads();
  for (int i = threadIdx.x; i < EE*DD; i += 256){
    const int e = i >> 6, d = i & 63;
    atomicAdd(&hf[(size_t)b*EE*DD + i], red[e*65 + d] + red[2080 + e*65 + d]);
  }
}

// ---------------- K14: ho preamble (LDS) + fused STGCN + hyper-combine; W fragments from LDS ----------------
// REQUIRES xin != xout (launcher ping-pongs): reads x[t-1] rows cross-tile.
__global__ __launch_bounds__(256, 2)
void k14_fused(const float* __restrict__ x,
               const float* __restrict__ W1, const float* __restrict__ b1,
               const float* __restrict__ W2, const float* __restrict__ b2,
               const float* __restrict__ lng, const float* __restrict__ lnb,
               const unsigned short* __restrict__ assign_hi,
               const unsigned short* __restrict__ assign_lo,
               const float* __restrict__ hf, const float* __restrict__ em,
               const float* __restrict__ hg, const float* __restrict__ hb,
               float* __restrict__ xout)
{
  // union: phase A {ems 4KB | hfs 8KB | hos 8KB} -> phase B {wlds 18.4KB}
  __shared__ __align__(16) unsigned char smem[20480];
  float* ems = (float*)smem;                   // [EE*EE]
  float* hfs = ems + EE*EE;                    // [EE*DD]
  float* hos = hfs + EE*DD;                    // [EE*DD]
  unsigned short* wlds = (unsigned short*)smem; // [2][64][WSTRIDE] bf16 (aliases all of the above)

  const int lane = threadIdx.x & 63;
  const int wid  = threadIdx.x >> 6;
  const int b    = blockIdx.x / CPB4;
  const int blk  = blockIdx.x % CPB4;
  const int l15  = lane & 15;
  const int lg   = lane >> 4;
  const int k0   = lg * 8;

  // ---- phase A: ho preamble (bit-identical math to former k3_edge) ----
  for (int i = threadIdx.x; i < EE*EE; i += 256) ems[i] = em[i];
  for (int i = threadIdx.x; i < EE*DD; i += 256) hfs[i] = hf[(size_t)b*EE*DD + i];
  __syncthreads();
  for (int i = threadIdx.x; i < EE*DD; i += 256){
    const int e = i >> 6, d = i & 63;
    float acc = 0.f;
    #pragma unroll
    for (int f = 0; f < EE; ++f) acc = fmaf(ems[e*EE+f], hfs[f*DD+d], acc);
    hos[i] = fmaxf(acc, 0.f) + hfs[e*DD+d];
  }
  __syncthreads();

  // ho fragments built from LDS (must complete before wlds overwrites hos)
  short8 bwh[4], bwl[4];
  #pragma unroll
  for (int nt = 0; nt < 4; ++nt){
    float v[8];
    #pragma unroll
    for (int j = 0; j < 8; ++j)
      v[j] = hos[(8*lg + j)*DD + l15 + 16*nt];
    bwh[nt] = pack_hi8(v);
    bwl[nt] = pack_lo8(v, bwh[nt]);
  }
  __syncthreads();

  // ---- phase B: stage W1/W2 as bf16 into LDS (same RNE conversion as before) ----
  {
    const float* Wm[2] = {W1, W2};
    for (int i = threadIdx.x; i < 2*DD*DD; i += 256){
      const int m = i >> 12;          // /4096
      const int rc = i & 4095;
      const int r = rc >> 6, c = rc & 63;
      wlds[m*(DD*WSTRIDE) + r*WSTRIDE + c] = bf16of(Wm[m][r*DD + c]);
    }
  }
  __syncthreads();

  float b1c[4], b2c[4], g1c[4], B1c[4], g2c[4], B2c[4];
  #pragma unroll
  for (int nt = 0; nt < 4; ++nt){
    b1c[nt] = b1[l15 + 16*nt];
    b2c[nt] = b2[l15 + 16*nt];
    g1c[nt] = lng[l15 + 16*nt];
    B1c[nt] = lnb[l15 + 16*nt];
    g2c[nt] = hg[l15 + 16*nt];
    B2c[nt] = hb[l15 + 16*nt];
  }

  const int tpb = MM / 16;                      // 768 tiles per batch; 2 tiles/wave at CPB4=96
  for (int tl = blk*4 + wid; tl < tpb; tl += CPB4*4){
    const size_t r0 = (size_t)b*MM + (size_t)tl*16;  // global row base
    const int t = (tl*16) >> 10;                // local frame index 0..11

    // ---- k1-part A-fragments ----
    const float* pc = x + (r0 + l15)*DD + k0;
    float4 a00 = *reinterpret_cast<const float4*>(pc);
    float4 a01 = *reinterpret_cast<const float4*>(pc + 4);
    float4 a10 = *reinterpret_cast<const float4*>(pc + 32);
    float4 a11 = *reinterpret_cast<const float4*>(pc + 36);
    if (t > 0){
      const float* pp = pc - (size_t)NN*DD;
      const float4 q00 = *reinterpret_cast<const float4*>(pp);
      const float4 q01 = *reinterpret_cast<const float4*>(pp + 4);
      const float4 q10 = *reinterpret_cast<const float4*>(pp + 32);
      const float4 q11 = *reinterpret_cast<const float4*>(pp + 36);
      a00.x = 0.5f*(a00.x+q00.x); a00.y = 0.5f*(a00.y+q00.y);
      a00.z = 0.5f*(a00.z+q00.z); a00.w = 0.5f*(a00.w+q00.w);
      a01.x = 0.5f*(a01.x+q01.x); a01.y = 0.5f*(a01.y+q01.y);
      a01.z = 0.5f*(a01.z+q01.z); a01.w = 0.5f*(a01.w+q01.w);
      a10.x = 0.5f*(a10.x+q10.x); a10.y = 0.5f*(a10.y+q10.y);
      a10.z = 0.5f*(a10.z+q10.z); a10.w = 0.5f*(a10.w+q10.w);
      a11.x = 0.5f*(a11.x+q11.x); a11.y = 0.5f*(a11.y+q11.y);
      a11.z = 0.5f*(a11.z+q11.z); a11.w = 0.5f*(a11.w+q11.w);
    } else {
      a00.x*=0.5f;a00.y*=0.5f;a00.z*=0.5f;a00.w*=0.5f;
      a01.x*=0.5f;a01.y*=0.5f;a01.z*=0.5f;a01.w*=0.5f;
      a10.x*=0.5f;a10.y*=0.5f;a10.z*=0.5f;a10.w*=0.5f;
      a11.x*=0.5f;a11.y*=0.5f;a11.z*=0.5f;a11.w*=0.5f;
    }
    // shared epilogue x loads (C-layout rows)
    float epi[4][4];
    #pragma unroll
    for (int q = 0; q < 4; ++q){
      const float* pr = x + (r0 + 4*lg + q)*DD + l15;
      #pragma unroll
      for (int nt = 0; nt < 4; ++nt) epi[q][nt] = pr[16*nt];
    }
    // k4-part A-fragments
    const short8 afh = *reinterpret_cast<const short8*>(assign_hi + (r0 + l15)*EE + 8*lg);
    const short8 afl = *reinterpret_cast<const short8*>(assign_lo + (r0 + l15)*EE + 8*lg);

    short8 af[2];
    {
      int4v w;
      w.x = cvt2(a00.x, a00.y); w.y = cvt2(a00.z, a00.w);
      w.z = cvt2(a01.x, a01.y); w.w = cvt2(a01.z, a01.w);
      af[0] = __builtin_bit_cast(short8, w);
      w.x = cvt2(a10.x, a10.y); w.y = cvt2(a10.z, a10.w);
      w.z = cvt2(a11.x, a11.y); w.w = cvt2(a11.z, a11.w);
      af[1] = __builtin_bit_cast(short8, w);
    }

    f32x4 acc1[2][4], acc4[4];
    #pragma unroll
    for (int m = 0; m < 2; ++m)
      #pragma unroll
      for (int nt = 0; nt < 4; ++nt) acc1[m][nt] = (f32x4){0.f,0.f,0.f,0.f};
    #pragma unroll
    for (int nt = 0; nt < 4; ++nt) acc4[nt] = (f32x4){0.f,0.f,0.f,0.f};

    // k1-part MFMAs with W fragments streamed from LDS
    #pragma unroll
    for (int kc = 0; kc < 2; ++kc){
      #pragma unroll
      for (int nt = 0; nt < 4; ++nt){
        const int off = (16*nt + l15)*WSTRIDE + 32*kc + 8*lg;
        const short8 w0 = *reinterpret_cast<const short8*>(wlds + off);
        const short8 w1 = *reinterpret_cast<const short8*>(wlds + DD*WSTRIDE + off);
        acc1[0][nt] = __builtin_amdgcn_mfma_f32_16x16x32_bf16(af[kc], w0, acc1[0][nt], 0, 0, 0);
        acc1[1][nt] = __builtin_amdgcn_mfma_f32_16x16x32_bf16(af[kc], w1, acc1[1][nt], 0, 0, 0);
      }
    }
    #pragma unroll
    for (int nt = 0; nt < 4; ++nt){
      acc4[nt] = __builtin_amdgcn_mfma_f32_16x16x32_bf16(afh, bwh[nt], acc4[nt], 0, 0, 0);
      acc4[nt] = __builtin_amdgcn_mfma_f32_16x16x32_bf16(afh, bwl[nt], acc4[nt], 0, 0, 0);
      acc4[nt] = __builtin_amdgcn_mfma_f32_16x16x32_bf16(afl, bwh[nt], acc4[nt], 0, 0, 0);
    }

    // ---- dual epilogue: LN1 (stgcn) and LN2 (hyper), interleaved shfl chains ----
    #pragma unroll
    for (int q = 0; q < 4; ++q){
      const size_t row = r0 + 4*lg + q;
      float s1[4], s2[4];
      float rs1 = 0.f, rs2 = 0.f;
      #pragma unroll
      for (int nt = 0; nt < 4; ++nt){
        const float g1 = acc1[0][nt][q] + b1c[nt];
        const float g2 = acc1[1][nt][q] + b2c[nt];
        s1[nt] = fmaxf(g1*g2, 0.f) + g1 + epi[q][nt];
        rs1 += s1[nt];
        s2[nt] = fmaxf(acc4[nt][q], 0.f) + epi[q][nt];
        rs2 += s2[nt];
      }
      #pragma unroll
      for (int off = 8; off; off >>= 1){ rs1 += __shfl_xor(rs1, off); rs2 += __shfl_xor(rs2, off); }
      const float m1 = rs1 * (1.f/DD);
      const float m2 = rs2 * (1.f/DD);
      float d1[4], d2[4]; float v1 = 0.f, v2 = 0.f;
      #pragma unroll
      for (int nt = 0; nt < 4; ++nt){
        d1[nt] = s1[nt] - m1; v1 = fmaf(d1[nt], d1[nt], v1);
        d2[nt] = s2[nt] - m2; v2 = fmaf(d2[nt], d2[nt], v2);
      }
      #pragma unroll
      for (int off = 8; off; off >>= 1){ v1 += __shfl_xor(v1, off); v2 += __shfl_xor(v2, off); }
      const float i1 = rsqrtf(v1 * (1.f/DD) + LN_EPS);
      const float i2 = rsqrtf(v2 * (1.f/DD) + LN_EPS);
      #pragma unroll
      for (int nt = 0; nt < 4; ++nt){
        const float o1 = d1[nt]*i1*g1c[nt] + B1c[nt];
        const float o2 = d2[nt]*i2*g2c[nt] + B2c[nt];
        xout[row*DD + l15 + 16*nt] = 0.5f*(o1 + o2);
      }
    }
  }
}

extern "C" void kernel_launch(void* const* d_in, const int* in_sizes, int n_in,
                              void* d_out, int out_size, void* d_ws, size_t ws_size,
                              hipStream_t stream)
{
  (void)in_sizes; (void)n_in; (void)out_size; (void)ws_size;
  const float* x0  = (const float*)d_in[0];
  const float* W1  = (const float*)d_in[1];
  const float* b1  = (const float*)d_in[2];
  const float* W2  = (const float*)d_in[3];
  const float* b2  = (const float*)d_in[4];
  const float* lng = (const float*)d_in[5];
  const float* lnb = (const float*)d_in[6];
  const float* clf = (const float*)d_in[7];
  const float* em  = (const float*)d_in[8];
  const float* hg  = (const float*)d_in[9];
  const float* hb  = (const float*)d_in[10];
  float* out = (float*)d_out;

  // workspace: x ping f32 | hf3 f32 [3][BB][EE*DD] (384 KB, one upfront memset) | assign hi/lo bf16
  float* ws_x = (float*)d_ws;
  float* hf3  = ws_x + (size_t)ROWS*DD;
  unsigned short* assign_hi = (unsigned short*)(hf3 + (size_t)3*BB*EE*DD);
  unsigned short* assign_lo = assign_hi + (size_t)ROWS*EE;

  // ping-pong so xin != xout at EVERY depth (k14 reads t-1 rows cross-tile):
  // depth 0: x0 -> d_out ; depth 1: d_out -> ws_x ; depth 2: ws_x -> d_out (final)
  const float* xin_seq[3]  = { x0, out, ws_x };
  float*       xout_seq[3] = { out, ws_x, out };

  hipMemsetAsync(hf3, 0, (size_t)3*BB*EE*DD*sizeof(float), stream);
  for (int i = 0; i < 3; ++i){
    const float* xin = xin_seq[i];
    float* xout = xout_seq[i];
    float* hf = hf3 + (size_t)i*BB*EE*DD;
    k2_hyper1<<<BB*CPB2N, 256, 0, stream>>>(xin, clf, assign_hi, assign_lo, hf);
    k14_fused<<<BB*CPB4, 256, 0, stream>>>(xin, W1 + i*DD*DD, b1 + i*DD,
                                           W2 + i*DD*DD, b2 + i*DD,
                                           lng + i*DD, lnb + i*DD,
                                           assign_hi, assign_lo, hf, em,
                                           hg, hb, xout);
  }
}

// Round 21
// 220.877 us; speedup vs baseline: 1.0770x; 1.0530x over previous
//
#include <hip/hip_runtime.h>

#define BB 16
#define TT 12
#define NN 1024
#define DD 64
#define EE 32
#define MM (TT*NN)          // 12288 rows per batch
#define ROWS (BB*MM)        // 196608 total rows
#define CPB2N 96            // k2 blocks per batch -> grid 1536; 1 chunk/wave
#define S_ITER (384/(CPB2N*4))   // chunks per wave
#define CPB4 64             // k14 blocks per batch -> grid 1024 = exactly 4 blocks/CU, 3 tiles/wave
#define LN_EPS 1e-5f

typedef __attribute__((ext_vector_type(8))) short short8;
typedef __attribute__((ext_vector_type(4))) float f32x4;
typedef __attribute__((ext_vector_type(4))) int   int4v;

// pack two f32 -> one dword of 2 bf16 (RNE), low = a, high = b
__device__ __forceinline__ int cvt2(float a, float b){
  int r;
  asm("v_cvt_pk_bf16_f32 %0, %1, %2" : "=v"(r) : "v"(a), "v"(b));
  return r;
}
__device__ __forceinline__ unsigned short bf16of(float a){
  return (unsigned short)(cvt2(a, a) & 0xffff);
}
__device__ __forceinline__ float f32of(unsigned short h){
  return __builtin_bit_cast(float, (unsigned int)h << 16);
}
__device__ __forceinline__ float lo16f(int w){ return __builtin_bit_cast(float, (unsigned int)w << 16); }
__device__ __forceinline__ float hi16f(int w){ return __builtin_bit_cast(float, (unsigned int)w & 0xffff0000u); }

__device__ __forceinline__ short8 pack_hi8(const float* v){
  int4v w;
  w.x = cvt2(v[0], v[1]); w.y = cvt2(v[2], v[3]);
  w.z = cvt2(v[4], v[5]); w.w = cvt2(v[6], v[7]);
  return __builtin_bit_cast(short8, w);
}
__device__ __forceinline__ short8 pack_lo8(const float* v, short8 hi){
  const int4v wh = __builtin_bit_cast(int4v, hi);
  float r[8];
  r[0] = v[0] - lo16f(wh.x); r[1] = v[1] - hi16f(wh.x);
  r[2] = v[2] - lo16f(wh.y); r[3] = v[3] - hi16f(wh.y);
  r[4] = v[4] - lo16f(wh.z); r[5] = v[5] - hi16f(wh.z);
  r[6] = v[6] - lo16f(wh.w); r[7] = v[7] - hi16f(wh.w);
  return pack_hi8(r);
}

// ---------------- K2: full-MFMA hyper stage 1; finishes with atomicAdd into hf ----------------
__global__ __launch_bounds__(256, 3)
void k2_hyper1(const float* __restrict__ x, const float* __restrict__ clf,
               unsigned short* __restrict__ assign_hi, unsigned short* __restrict__ assign_lo,
               float* __restrict__ hf)
{
  __shared__ __align__(16) float lbuf[4224];   // union: amat 4x[32][33] | red 2x[32][65]
  const int lane = threadIdx.x & 63;
  const int wid  = threadIdx.x >> 6;
  const int l15  = lane & 15;
  const int lg   = lane >> 4;
  const int b    = blockIdx.x / CPB2N;
  const int blk  = blockIdx.x % CPB2N;
  float* amat = lbuf + wid*1056;               // [32][33] f32 per wave

  short8 bch[2][2], bcl[2][2];
  #pragma unroll
  for (int kc = 0; kc < 2; ++kc)
    #pragma unroll
    for (int nt = 0; nt < 2; ++nt){
      float v[8];
      #pragma unroll
      for (int j = 0; j < 8; ++j)
        v[j] = clf[(size_t)(32*kc + 8*lg + j)*EE + 16*nt + l15];
      bch[kc][nt] = pack_hi8(v);
      bcl[kc][nt] = pack_lo8(v, bch[kc][nt]);
    }

  f32x4 acc2[2][4];
  #pragma unroll
  for (int et = 0; et < 2; ++et)
    #pragma unroll
    for (int dt = 0; dt < 4; ++dt) acc2[et][dt] = (f32x4){0.f,0.f,0.f,0.f};

  const int wslot = blk*4 + wid;               // 0..CPB2N*4-1
  #pragma unroll 1
  for (int s = 0; s < S_ITER; ++s){
    const int c = wslot + s*(CPB2N*4);         // chunk id, covers 0..383 exactly once
    const size_t grb = (size_t)b*MM + (size_t)c*32;

    #pragma unroll 1
    for (int h = 0; h < 2; ++h){
      short8 axh[2], axl[2];
      #pragma unroll
      for (int kc = 0; kc < 2; ++kc){
        const float* p = x + (grb + 16*h + l15)*DD + 32*kc + 8*lg;
        float v[8];
        const float4 p0 = *reinterpret_cast<const float4*>(p);
        const float4 p1 = *reinterpret_cast<const float4*>(p + 4);
        v[0]=p0.x; v[1]=p0.y; v[2]=p0.z; v[3]=p0.w;
        v[4]=p1.x; v[5]=p1.y; v[6]=p1.z; v[7]=p1.w;
        axh[kc] = pack_hi8(v); axl[kc] = pack_lo8(v, axh[kc]);
      }
      f32x4 accL[2] = {(f32x4){0.f,0.f,0.f,0.f},(f32x4){0.f,0.f,0.f,0.f}};
      #pragma unroll
      for (int kc = 0; kc < 2; ++kc)
        #pragma unroll
        for (int nt = 0; nt < 2; ++nt){
          accL[nt] = __builtin_amdgcn_mfma_f32_16x16x32_bf16(axh[kc], bch[kc][nt], accL[nt], 0, 0, 0);
          accL[nt] = __builtin_amdgcn_mfma_f32_16x16x32_bf16(axh[kc], bcl[kc][nt], accL[nt], 0, 0, 0);
          accL[nt] = __builtin_amdgcn_mfma_f32_16x16x32_bf16(axl[kc], bch[kc][nt], accL[nt], 0, 0, 0);
        }
      #pragma unroll
      for (int q = 0; q < 4; ++q){
        const float l0 = accL[0][q], l1 = accL[1][q];
        float mx = fmaxf(l0, l1);
        #pragma unroll
        for (int off = 8; off; off >>= 1) mx = fmaxf(mx, __shfl_xor(mx, off));
        const float e0 = expf(l0 - mx), e1 = expf(l1 - mx);
        float sm = e0 + e1;
        #pragma unroll
        for (int off = 8; off; off >>= 1) sm += __shfl_xor(sm, off);
        const float inv = 1.f / sm;
        const float a0 = e0*inv, a1 = e1*inv;
        const int rloc = 16*h + 4*lg + q;
        const size_t row = grb + rloc;
        const unsigned short h0 = bf16of(a0);
        const unsigned short h1 = bf16of(a1);
        assign_hi[row*EE + l15]      = h0;
        assign_hi[row*EE + 16 + l15] = h1;
        assign_lo[row*EE + l15]      = bf16of(a0 - f32of(h0));
        assign_lo[row*EE + 16 + l15] = bf16of(a1 - f32of(h1));
        amat[rloc*33 + l15]      = a0;
        amat[rloc*33 + 16 + l15] = a1;
      }
    }
    __builtin_amdgcn_wave_barrier();
    short8 a2h[2], a2l[2];
    #pragma unroll
    for (int et = 0; et < 2; ++et){
      float v[8];
      #pragma unroll
      for (int j = 0; j < 8; ++j)
        v[j] = amat[(8*lg + j)*33 + 16*et + l15];
      a2h[et] = pack_hi8(v); a2l[et] = pack_lo8(v, a2h[et]);
    }
    #pragma unroll
    for (int dt = 0; dt < 4; ++dt){
      float v[8];
      #pragma unroll
      for (int j = 0; j < 8; ++j)
        v[j] = x[(grb + 8*lg + j)*DD + 16*dt + l15];
      const short8 b2 = pack_hi8(v);
      #pragma unroll
      for (int et = 0; et < 2; ++et){
        acc2[et][dt] = __builtin_amdgcn_mfma_f32_16x16x32_bf16(a2h[et], b2, acc2[et][dt], 0, 0, 0);
        acc2[et][dt] = __builtin_amdgcn_mfma_f32_16x16x32_bf16(a2l[et], b2, acc2[et][dt], 0, 0, 0);
      }
    }
    __builtin_amdgcn_wave_barrier();
  }

  __syncthreads();
  float* red = lbuf;
  if (wid < 2){
    #pragma unroll
    for (int et = 0; et < 2; ++et)
      #pragma unroll
      for (int dt = 0; dt < 4; ++dt)
        #pragma unroll
        for (int q = 0; q < 4; ++q)
          red[wid*2080 + (16*et + 4*lg + q)*65 + 16*dt + l15] = acc2[et][dt][q];
  }
  __syncthreads();
  if (wid >= 2){
    #pragma unroll
    for (int et = 0; et < 2; ++et)
      #pragma unroll
      for (int dt = 0; dt < 4; ++dt)
        #pragma unroll
        for (int q = 0; q < 4; ++q)
          red[(wid-2)*2080 + (16*et + 4*lg + q)*65 + 16*dt + l15] += acc2[et][dt][q];
  }
  __syncthreads();
  for (int i = threadIdx.x; i < EE*DD; i += 256){
    const int e = i >> 6, d = i & 63;
    atomicAdd(&hf[(size_t)b*EE*DD + i], red[e*65 + d] + red[2080 + e*65 + d]);
  }
}

// ---------------- K14: ho preamble (LDS) + fused STGCN + hyper-combine (round-16/18 version) ----------------
// REQUIRES xin != xout (launcher ping-pongs): reads x[t-1] rows cross-tile.
__global__ __launch_bounds__(256, 2)
void k14_fused(const float* __restrict__ x,
               const float* __restrict__ W1, const float* __restrict__ b1,
               const float* __restrict__ W2, const float* __restrict__ b2,
               const float* __restrict__ lng, const float* __restrict__ lnb,
               const unsigned short* __restrict__ assign_hi,
               const unsigned short* __restrict__ assign_lo,
               const float* __restrict__ hf, const float* __restrict__ em,
               const float* __restrict__ hg, const float* __restrict__ hb,
               float* __restrict__ xout)
{
  __shared__ float ems[EE*EE];
  __shared__ float hfs[EE*DD];
  __shared__ float hos[EE*DD];
  const int lane = threadIdx.x & 63;
  const int wid  = threadIdx.x >> 6;
  const int b    = blockIdx.x / CPB4;
  const int blk  = blockIdx.x % CPB4;
  const int l15  = lane & 15;
  const int lg   = lane >> 4;
  const int k0   = lg * 8;

  // ---- ho preamble (bit-identical math to former k3_edge) ----
  for (int i = threadIdx.x; i < EE*EE; i += 256) ems[i] = em[i];
  for (int i = threadIdx.x; i < EE*DD; i += 256) hfs[i] = hf[(size_t)b*EE*DD + i];
  __syncthreads();
  for (int i = threadIdx.x; i < EE*DD; i += 256){
    const int e = i >> 6, d = i & 63;
    float acc = 0.f;
    #pragma unroll
    for (int f = 0; f < EE; ++f) acc = fmaf(ems[e*EE+f], hfs[f*DD+d], acc);
    hos[i] = fmaxf(acc, 0.f) + hfs[e*DD+d];
  }
  __syncthreads();

  // ho fragments built from LDS
  short8 bwh[4], bwl[4];
  #pragma unroll
  for (int nt = 0; nt < 4; ++nt){
    float v[8];
    #pragma unroll
    for (int j = 0; j < 8; ++j)
      v[j] = hos[(8*lg + j)*DD + l15 + 16*nt];
    bwh[nt] = pack_hi8(v);
    bwl[nt] = pack_lo8(v, bwh[nt]);
  }

  // W fragments (k1 part) — in registers (measured optimum)
  short8 bw[2][4][2];
  const float* Wm[2] = {W1, W2};
  #pragma unroll
  for (int m = 0; m < 2; ++m)
    #pragma unroll
    for (int nt = 0; nt < 4; ++nt)
      #pragma unroll
      for (int kc = 0; kc < 2; ++kc){
        const float* src = Wm[m] + (size_t)(16*nt + l15)*DD + 32*kc + k0;
        const float4 p0 = *reinterpret_cast<const float4*>(src);
        const float4 p1 = *reinterpret_cast<const float4*>(src + 4);
        int4v w;
        w.x = cvt2(p0.x, p0.y); w.y = cvt2(p0.z, p0.w);
        w.z = cvt2(p1.x, p1.y); w.w = cvt2(p1.z, p1.w);
        bw[m][nt][kc] = __builtin_bit_cast(short8, w);
      }

  float b1c[4], b2c[4], g1c[4], B1c[4], g2c[4], B2c[4];
  #pragma unroll
  for (int nt = 0; nt < 4; ++nt){
    b1c[nt] = b1[l15 + 16*nt];
    b2c[nt] = b2[l15 + 16*nt];
    g1c[nt] = lng[l15 + 16*nt];
    B1c[nt] = lnb[l15 + 16*nt];
    g2c[nt] = hg[l15 + 16*nt];
    B2c[nt] = hb[l15 + 16*nt];
  }

  const int tpb = MM / 16;                      // 768 tiles per batch; 3 tiles/wave at CPB4=64
  for (int tl = blk*4 + wid; tl < tpb; tl += CPB4*4){
    const size_t r0 = (size_t)b*MM + (size_t)tl*16;  // global row base
    const int t = (tl*16) >> 10;                // local frame index 0..11

    // ---- k1-part A-fragments ----
    const float* pc = x + (r0 + l15)*DD + k0;
    float4 a00 = *reinterpret_cast<const float4*>(pc);
    float4 a01 = *reinterpret_cast<const float4*>(pc + 4);
    float4 a10 = *reinterpret_cast<const float4*>(pc + 32);
    float4 a11 = *reinterpret_cast<const float4*>(pc + 36);
    if (t > 0){
      const float* pp = pc - (size_t)NN*DD;
      const float4 q00 = *reinterpret_cast<const float4*>(pp);
      const float4 q01 = *reinterpret_cast<const float4*>(pp + 4);
      const float4 q10 = *reinterpret_cast<const float4*>(pp + 32);
      const float4 q11 = *reinterpret_cast<const float4*>(pp + 36);
      a00.x = 0.5f*(a00.x+q00.x); a00.y = 0.5f*(a00.y+q00.y);
      a00.z = 0.5f*(a00.z+q00.z); a00.w = 0.5f*(a00.w+q00.w);
      a01.x = 0.5f*(a01.x+q01.x); a01.y = 0.5f*(a01.y+q01.y);
      a01.z = 0.5f*(a01.z+q01.z); a01.w = 0.5f*(a01.w+q01.w);
      a10.x = 0.5f*(a10.x+q10.x); a10.y = 0.5f*(a10.y+q10.y);
      a10.z = 0.5f*(a10.z+q10.z); a10.w = 0.5f*(a10.w+q10.w);
      a11.x = 0.5f*(a11.x+q11.x); a11.y = 0.5f*(a11.y+q11.y);
      a11.z = 0.5f*(a11.z+q11.z); a11.w = 0.5f*(a11.w+q11.w);
    } else {
      a00.x*=0.5f;a00.y*=0.5f;a00.z*=0.5f;a00.w*=0.5f;
      a01.x*=0.5f;a01.y*=0.5f;a01.z*=0.5f;a01.w*=0.5f;
      a10.x*=0.5f;a10.y*=0.5f;a10.z*=0.5f;a10.w*=0.5f;
      a11.x*=0.5f;a11.y*=0.5f;a11.z*=0.5f;a11.w*=0.5f;
    }
    // shared epilogue x loads (C-layout rows)
    float epi[4][4];
    #pragma unroll
    for (int q = 0; q < 4; ++q){
      const float* pr = x + (r0 + 4*lg + q)*DD + l15;
      #pragma unroll
      for (int nt = 0; nt < 4; ++nt) epi[q][nt] = pr[16*nt];
    }
    // k4-part A-fragments
    const short8 afh = *reinterpret_cast<const short8*>(assign_hi + (r0 + l15)*EE + 8*lg);
    const short8 afl = *reinterpret_cast<const short8*>(assign_lo + (r0 + l15)*EE + 8*lg);

    short8 af[2];
    {
      int4v w;
      w.x = cvt2(a00.x, a00.y); w.y = cvt2(a00.z, a00.w);
      w.z = cvt2(a01.x, a01.y); w.w = cvt2(a01.z, a01.w);
      af[0] = __builtin_bit_cast(short8, w);
      w.x = cvt2(a10.x, a10.y); w.y = cvt2(a10.z, a10.w);
      w.z = cvt2(a11.x, a11.y); w.w = cvt2(a11.z, a11.w);
      af[1] = __builtin_bit_cast(short8, w);
    }

    f32x4 acc1[2][4], acc4[4];
    #pragma unroll
    for (int m = 0; m < 2; ++m)
      #pragma unroll
      for (int nt = 0; nt < 4; ++nt) acc1[m][nt] = (f32x4){0.f,0.f,0.f,0.f};
    #pragma unroll
    for (int nt = 0; nt < 4; ++nt) acc4[nt] = (f32x4){0.f,0.f,0.f,0.f};

    #pragma unroll
    for (int kc = 0; kc < 2; ++kc){
      #pragma unroll
      for (int nt = 0; nt < 4; ++nt){
        acc1[0][nt] = __builtin_amdgcn_mfma_f32_16x16x32_bf16(af[kc], bw[0][nt][kc], acc1[0][nt], 0, 0, 0);
        acc1[1][nt] = __builtin_amdgcn_mfma_f32_16x16x32_bf16(af[kc], bw[1][nt][kc], acc1[1][nt], 0, 0, 0);
      }
    }
    #pragma unroll
    for (int nt = 0; nt < 4; ++nt){
      acc4[nt] = __builtin_amdgcn_mfma_f32_16x16x32_bf16(afh, bwh[nt], acc4[nt], 0, 0, 0);
      acc4[nt] = __builtin_amdgcn_mfma_f32_16x16x32_bf16(afh, bwl[nt], acc4[nt], 0, 0, 0);
      acc4[nt] = __builtin_amdgcn_mfma_f32_16x16x32_bf16(afl, bwh[nt], acc4[nt], 0, 0, 0);
    }

    // ---- dual epilogue: LN1 (stgcn) and LN2 (hyper), interleaved shfl chains ----
    #pragma unroll
    for (int q = 0; q < 4; ++q){
      const size_t row = r0 + 4*lg + q;
      float s1[4], s2[4];
      float rs1 = 0.f, rs2 = 0.f;
      #pragma unroll
      for (int nt = 0; nt < 4; ++nt){
        const float g1 = acc1[0][nt][q] + b1c[nt];
        const float g2 = acc1[1][nt][q] + b2c[nt];
        s1[nt] = fmaxf(g1*g2, 0.f) + g1 + epi[q][nt];
        rs1 += s1[nt];
        s2[nt] = fmaxf(acc4[nt][q], 0.f) + epi[q][nt];
        rs2 += s2[nt];
      }
      #pragma unroll
      for (int off = 8; off; off >>= 1){ rs1 += __shfl_xor(rs1, off); rs2 += __shfl_xor(rs2, off); }
      const float m1 = rs1 * (1.f/DD);
      const float m2 = rs2 * (1.f/DD);
      float d1[4], d2[4]; float v1 = 0.f, v2 = 0.f;
      #pragma unroll
      for (int nt = 0; nt < 4; ++nt){
        d1[nt] = s1[nt] - m1; v1 = fmaf(d1[nt], d1[nt], v1);
        d2[nt] = s2[nt] - m2; v2 = fmaf(d2[nt], d2[nt], v2);
      }
      #pragma unroll
      for (int off = 8; off; off >>= 1){ v1 += __shfl_xor(v1, off); v2 += __shfl_xor(v2, off); }
      const float i1 = rsqrtf(v1 * (1.f/DD) + LN_EPS);
      const float i2 = rsqrtf(v2 * (1.f/DD) + LN_EPS);
      #pragma unroll
      for (int nt = 0; nt < 4; ++nt){
        const float o1 = d1[nt]*i1*g1c[nt] + B1c[nt];
        const float o2 = d2[nt]*i2*g2c[nt] + B2c[nt];
        xout[row*DD + l15 + 16*nt] = 0.5f*(o1 + o2);
      }
    }
  }
}

extern "C" void kernel_launch(void* const* d_in, const int* in_sizes, int n_in,
                              void* d_out, int out_size, void* d_ws, size_t ws_size,
                              hipStream_t stream)
{
  (void)in_sizes; (void)n_in; (void)out_size; (void)ws_size;
  const float* x0  = (const float*)d_in[0];
  const float* W1  = (const float*)d_in[1];
  const float* b1  = (const float*)d_in[2];
  const float* W2  = (const float*)d_in[3];
  const float* b2  = (const float*)d_in[4];
  const float* lng = (const float*)d_in[5];
  const float* lnb = (const float*)d_in[6];
  const float* clf = (const float*)d_in[7];
  const float* em  = (const float*)d_in[8];
  const float* hg  = (const float*)d_in[9];
  const float* hb  = (const float*)d_in[10];
  float* out = (float*)d_out;

  // workspace: x ping f32 | hf3 f32 [3][BB][EE*DD] (384 KB, one upfront memset) | assign hi/lo bf16
  float* ws_x = (float*)d_ws;
  float* hf3  = ws_x + (size_t)ROWS*DD;
  unsigned short* assign_hi = (unsigned short*)(hf3 + (size_t)3*BB*EE*DD);
  unsigned short* assign_lo = assign_hi + (size_t)ROWS*EE;

  // ping-pong so xin != xout at EVERY depth (k14 reads t-1 rows cross-tile):
  // depth 0: x0 -> d_out ; depth 1: d_out -> ws_x ; depth 2: ws_x -> d_out (final)
  const float* xin_seq[3]  = { x0, out, ws_x };
  float*       xout_seq[3] = { out, ws_x, out };

  hipMemsetAsync(hf3, 0, (size_t)3*BB*EE*DD*sizeof(float), stream);
  for (int i = 0; i < 3; ++i){
    const float* xin = xin_seq[i];
    float* xout = xout_seq[i];
    float* hf = hf3 + (size_t)i*BB*EE*DD;
    k2_hyper1<<<BB*CPB2N, 256, 0, stream>>>(xin, clf, assign_hi, assign_lo, hf);
    k14_fused<<<BB*CPB4, 256, 0, stream>>>(xin, W1 + i*DD*DD, b1 + i*DD,
                                           W2 + i*DD*DD, b2 + i*DD,
                                           lng + i*DD, lnb + i*DD,
                                           assign_hi, assign_lo, hf, em,
                                           hg, hb, xout);
  }
}